// Round 1
// baseline (267.431 us; speedup 1.0000x reference)
//
#include <hip/hip_runtime.h>

// Problem constants (fixed by setup_inputs)
constexpr int NB  = 4;     // batch
constexpr int NPT = 2048;  // points (N)
constexpr int KNN = 32;    // neighbors (K)
constexpr int CIN = 6;     // in_channels
constexpr int CF  = 64;    // feat channels
constexpr int CO  = 64;    // out channels
constexpr float EPS = 1e-5f;
constexpr int LS = 36;     // padded LDS row stride in floats (16B-aligned rows, conflict-free)

struct Params {
  const float *x, *y, *points, *feat;
  const float *Wq, *Wpos1, *Wpos2, *Wattn, *Wlin, *Wres;
  const float *gq, *bq, *mq, *vq;
  const float *gp, *bp, *mp, *vp;
  const float *ga, *ba, *ma, *va;
  const float *g1, *b1, *m1, *v1;
  const float *gl, *bl, *ml, *vl;
  const float *gr, *br, *mr, *vr;
  float *out;
};

__global__ __launch_bounds__(256) void fused_pt_attn(Params p) {
  const int bn = blockIdx.x;
  const int b  = bn >> 11;          // NPT == 2048
  const int n  = bn & (NPT - 1);
  const int tid = threadIdx.x;

  __shared__ __align__(16) float s_y[CF * LS];     // y[b,:,n,:]
  __shared__ __align__(16) float s_attn[CF * LS];  // softmax output; reused as h after phase 3
  __shared__ __align__(16) float s_x[CIN * KNN];   // x[b,:,n,:]
  __shared__ float s_xq[CF];
  __shared__ float s_pos[CIN];
  __shared__ float s_feat[CF / 2];
  __shared__ float s_pts[CIN / 2];
  __shared__ float s_w2[CF * CIN];                 // Wpos2

  // ---------------- phase 0: stage inputs ----------------
  {
    const float *ybase = p.y + ((size_t)(b * CF) * NPT + n) * KNN;
#pragma unroll
    for (int r = 0; r < 8; ++r) {
      const int idx = r * 256 + tid;
      const int c = idx >> 5, k = idx & 31;
      s_y[c * LS + k] = ybase[(size_t)c * NPT * KNN + k];
    }
    if (tid < CIN * KNN) {
      const int i = tid >> 5, k = tid & 31;
      s_x[tid] = p.x[(((size_t)b * CIN + i) * NPT + n) * KNN + k];
    }
    if (tid >= 192 && tid < 192 + CF / 2) {
      const int c = tid - 192;
      s_feat[c] = p.feat[((size_t)b * (CF / 2) + c) * NPT + n];
    }
    if (tid >= 224 && tid < 224 + CIN / 2) {
      const int i = tid - 224;
      s_pts[i] = p.points[((size_t)b * (CIN / 2) + i) * NPT + n];
    }
    for (int t = tid; t < CF * CIN; t += 256) s_w2[t] = p.Wpos2[t];
  }
  __syncthreads();

  // ---------------- phase 1: x_q (BN+lrelu) and pos (BN+lrelu) ----------------
  if (tid < CF) {
    float acc = 0.f;
    const float *wrow = p.Wq + tid * (CF / 2);
#pragma unroll
    for (int i = 0; i < CF / 2; i += 4) {
      const float4 w = *(const float4 *)(wrow + i);
      acc += w.x * s_feat[i] + w.y * s_feat[i + 1] + w.z * s_feat[i + 2] + w.w * s_feat[i + 3];
    }
    const float s = p.gq[tid] * rsqrtf(p.vq[tid] + EPS);
    const float v = acc * s + (p.bq[tid] - p.mq[tid] * s);
    s_xq[tid] = v > 0.f ? v : 0.2f * v;
  } else if (tid < CF + CIN) {
    const int i = tid - CF;
    float acc = 0.f;
#pragma unroll
    for (int ci = 0; ci < CIN / 2; ++ci) acc += p.Wpos1[i * (CIN / 2) + ci] * s_pts[ci];
    const float s = p.gp[i] * rsqrtf(p.vp[i] + EPS);
    const float v = acc * s + (p.bp[i] - p.mp[i] * s);
    s_pos[i] = v > 0.f ? v : 0.2f * v;
  }
  __syncthreads();

  // thread mapping for phases 2..4: tid = row*4 + kg ; each thread owns 8 consecutive k
  const int kg = tid & 3;
  const int k0 = kg * 8;

  // ---------------- phase 2: attn_pre + softmax over k ----------------
  {
    const int c = tid >> 2;
    float w2[CIN];
#pragma unroll
    for (int i = 0; i < CIN; ++i) w2[i] = s_w2[c * CIN + i];
    const float xq = s_xq[c];
    float pre[8];
#pragma unroll
    for (int m = 0; m < 8; ++m) {
      const int k = k0 + m;
      float v = xq - s_y[c * LS + k];
#pragma unroll
      for (int i = 0; i < CIN; ++i) v += w2[i] * (s_pos[i] - s_x[i * KNN + k]);
      pre[m] = v * 0.125f;  // 1/sqrt(Cf)
    }
    float mx = pre[0];
#pragma unroll
    for (int m = 1; m < 8; ++m) mx = fmaxf(mx, pre[m]);
    mx = fmaxf(mx, __shfl_xor(mx, 1));
    mx = fmaxf(mx, __shfl_xor(mx, 2));
    float sum = 0.f;
#pragma unroll
    for (int m = 0; m < 8; ++m) { pre[m] = __expf(pre[m] - mx); sum += pre[m]; }
    sum += __shfl_xor(sum, 1);
    sum += __shfl_xor(sum, 2);
    const float inv = 1.f / sum;
#pragma unroll
    for (int m = 0; m < 8; ++m) s_attn[c * LS + k0 + m] = pre[m] * inv;
  }
  __syncthreads();

  // ---------------- phase 3: WA = Wattn@attn, BN_a, contract with x, BN_1+lrelu ----------------
  const int o = tid >> 2;
  float h[8];
  {
    float wa[6][8];
#pragma unroll
    for (int i = 0; i < 6; ++i)
#pragma unroll
      for (int m = 0; m < 8; ++m) wa[i][m] = 0.f;

    const float *wbase = p.Wattn + (size_t)(o * CIN) * CF;
#pragma unroll 2
    for (int c4 = 0; c4 < 16; ++c4) {
      float4 w4[6];
#pragma unroll
      for (int i = 0; i < 6; ++i)
        w4[i] = *(const float4 *)(wbase + i * CF + c4 * 4);

#define CC_STEP(COMP, CIDX)                                                   \
      {                                                                       \
        const int c = c4 * 4 + (CIDX);                                        \
        const float4 a0 = *(const float4 *)(s_attn + c * LS + k0);            \
        const float4 a1 = *(const float4 *)(s_attn + c * LS + k0 + 4);        \
        _Pragma("unroll")                                                     \
        for (int i = 0; i < 6; ++i) {                                         \
          const float w = w4[i].COMP;                                         \
          wa[i][0] = fmaf(w, a0.x, wa[i][0]);                                 \
          wa[i][1] = fmaf(w, a0.y, wa[i][1]);                                 \
          wa[i][2] = fmaf(w, a0.z, wa[i][2]);                                 \
          wa[i][3] = fmaf(w, a0.w, wa[i][3]);                                 \
          wa[i][4] = fmaf(w, a1.x, wa[i][4]);                                 \
          wa[i][5] = fmaf(w, a1.y, wa[i][5]);                                 \
          wa[i][6] = fmaf(w, a1.z, wa[i][6]);                                 \
          wa[i][7] = fmaf(w, a1.w, wa[i][7]);                                 \
        }                                                                     \
      }
      CC_STEP(x, 0)
      CC_STEP(y, 1)
      CC_STEP(z, 2)
      CC_STEP(w, 3)
#undef CC_STEP
    }

    float acc[8];
#pragma unroll
    for (int m = 0; m < 8; ++m) acc[m] = 0.f;
#pragma unroll
    for (int i = 0; i < 6; ++i) {
      const int j = o * CIN + i;
      const float s  = p.ga[j] * rsqrtf(p.va[j] + EPS);
      const float bb = p.ba[j] - p.ma[j] * s;
#pragma unroll
      for (int m = 0; m < 8; ++m)
        acc[m] = fmaf(fmaf(s, wa[i][m], bb), s_x[i * KNN + k0 + m], acc[m]);
    }
    const float s1  = p.g1[o] * rsqrtf(p.v1[o] + EPS);
    const float b1o = p.b1[o] - p.m1[o] * s1;
#pragma unroll
    for (int m = 0; m < 8; ++m) {
      const float t = fmaf(s1, acc[m], b1o);
      h[m] = t > 0.f ? t : 0.2f * t;
    }
  }
  __syncthreads();  // all reads of s_attn done
#pragma unroll
  for (int m = 0; m < 8; ++m) s_attn[o * LS + k0 + m] = h[m];  // s_h aliases s_attn
  __syncthreads();

  // ---------------- phase 4: Wlin@h (BN_l) + Wres@y (BN_r), lrelu, store ----------------
  {
    float acc2[8], acc3[8];
#pragma unroll
    for (int m = 0; m < 8; ++m) { acc2[m] = 0.f; acc3[m] = 0.f; }
    const float *wl = p.Wlin + (size_t)o * CF;
    const float *wr = p.Wres + (size_t)o * CF;
#pragma unroll 2
    for (int c4 = 0; c4 < 16; ++c4) {
      const float4 l4 = *(const float4 *)(wl + c4 * 4);
      const float4 r4 = *(const float4 *)(wr + c4 * 4);
#define CC2(COMP, CIDX)                                                       \
      {                                                                       \
        const int c = c4 * 4 + (CIDX);                                        \
        const float4 h0 = *(const float4 *)(s_attn + c * LS + k0);            \
        const float4 h1 = *(const float4 *)(s_attn + c * LS + k0 + 4);        \
        const float4 y0 = *(const float4 *)(s_y + c * LS + k0);               \
        const float4 y1 = *(const float4 *)(s_y + c * LS + k0 + 4);           \
        const float a = l4.COMP, r = r4.COMP;                                 \
        acc2[0] = fmaf(a, h0.x, acc2[0]); acc3[0] = fmaf(r, y0.x, acc3[0]);   \
        acc2[1] = fmaf(a, h0.y, acc2[1]); acc3[1] = fmaf(r, y0.y, acc3[1]);   \
        acc2[2] = fmaf(a, h0.z, acc2[2]); acc3[2] = fmaf(r, y0.z, acc3[2]);   \
        acc2[3] = fmaf(a, h0.w, acc2[3]); acc3[3] = fmaf(r, y0.w, acc3[3]);   \
        acc2[4] = fmaf(a, h1.x, acc2[4]); acc3[4] = fmaf(r, y1.x, acc3[4]);   \
        acc2[5] = fmaf(a, h1.y, acc2[5]); acc3[5] = fmaf(r, y1.y, acc3[5]);   \
        acc2[6] = fmaf(a, h1.z, acc2[6]); acc3[6] = fmaf(r, y1.z, acc3[6]);   \
        acc2[7] = fmaf(a, h1.w, acc2[7]); acc3[7] = fmaf(r, y1.w, acc3[7]);   \
      }
      CC2(x, 0)
      CC2(y, 1)
      CC2(z, 2)
      CC2(w, 3)
#undef CC2
    }
    const float sl  = p.gl[o] * rsqrtf(p.vl[o] + EPS);
    const float blo = p.bl[o] - p.ml[o] * sl;
    const float sr  = p.gr[o] * rsqrtf(p.vr[o] + EPS);
    const float bro = p.br[o] - p.mr[o] * sr;
    float *obase = p.out + (((size_t)b * CO + o) * NPT + n) * KNN + k0;
    float r[8];
#pragma unroll
    for (int m = 0; m < 8; ++m) {
      const float v = fmaf(sl, acc2[m], blo) + fmaf(sr, acc3[m], bro);
      r[m] = v > 0.f ? v : 0.2f * v;
    }
    *(float4 *)(obase)     = make_float4(r[0], r[1], r[2], r[3]);
    *(float4 *)(obase + 4) = make_float4(r[4], r[5], r[6], r[7]);
  }
}

extern "C" void kernel_launch(void *const *d_in, const int *in_sizes, int n_in,
                              void *d_out, int out_size, void *d_ws, size_t ws_size,
                              hipStream_t stream) {
  Params p;
  p.x      = (const float *)d_in[0];
  p.y      = (const float *)d_in[1];
  p.points = (const float *)d_in[2];
  p.feat   = (const float *)d_in[3];
  p.Wq     = (const float *)d_in[4];
  p.Wpos1  = (const float *)d_in[5];
  p.Wpos2  = (const float *)d_in[6];
  p.Wattn  = (const float *)d_in[7];
  p.Wlin   = (const float *)d_in[8];
  p.Wres   = (const float *)d_in[9];
  p.gq = (const float *)d_in[10]; p.bq = (const float *)d_in[11];
  p.mq = (const float *)d_in[12]; p.vq = (const float *)d_in[13];
  p.gp = (const float *)d_in[14]; p.bp = (const float *)d_in[15];
  p.mp = (const float *)d_in[16]; p.vp = (const float *)d_in[17];
  p.ga = (const float *)d_in[18]; p.ba = (const float *)d_in[19];
  p.ma = (const float *)d_in[20]; p.va = (const float *)d_in[21];
  p.g1 = (const float *)d_in[22]; p.b1 = (const float *)d_in[23];
  p.m1 = (const float *)d_in[24]; p.v1 = (const float *)d_in[25];
  p.gl = (const float *)d_in[26]; p.bl = (const float *)d_in[27];
  p.ml = (const float *)d_in[28]; p.vl = (const float *)d_in[29];
  p.gr = (const float *)d_in[30]; p.br = (const float *)d_in[31];
  p.mr = (const float *)d_in[32]; p.vr = (const float *)d_in[33];
  p.out = (float *)d_out;

  fused_pt_attn<<<dim3(NB * NPT), dim3(256), 0, stream>>>(p);
}

// Round 2
// 86.146 us; speedup vs baseline: 3.1044x; 3.1044x over previous
//
#include <hip/hip_runtime.h>

// Problem constants (fixed by setup_inputs)
constexpr int NB  = 4;     // batch
constexpr int NPT = 2048;  // points (N)
constexpr int KNN = 32;    // neighbors (K)
constexpr int CIN = 6;     // in_channels
constexpr int CF  = 64;    // feat channels
constexpr int CO  = 64;    // out channels
constexpr float EPS = 1e-5f;
constexpr int LS = 37;     // padded LDS row stride (floats) — bank-balanced scalar access

typedef short bf16x8 __attribute__((ext_vector_type(8)));   // 8 bf16 in 4 VGPRs
typedef float f32x4  __attribute__((ext_vector_type(4)));

// ---------------- workspace layout (bytes) ----------------
// 0      : WA_frag  bf16[6*4*2*64*8]  = 24576 elems (49152 B)
// 49152  : WL_frag  bf16[4*2*64*8]    =  4096 elems ( 8192 B)
// 57344  : WR_frag  bf16[4*2*64*8]    =  4096 elems ( 8192 B)
// 65536  : sa_perm  f32[384]
// 67072  : ba_perm  f32[384]
// 68608  : bnf      f32[6*64]  (s1,b1,sl,bl,sr,br folded)
constexpr size_t WS_WA  = 0;
constexpr size_t WS_WL  = 49152;
constexpr size_t WS_WR  = 57344;
constexpr size_t WS_SA  = 65536;
constexpr size_t WS_BA  = 67072;
constexpr size_t WS_BNF = 68608;

__device__ inline unsigned short bf16_rne(float f) {
  unsigned u = __builtin_bit_cast(unsigned, f);
  u += 0x7fffu + ((u >> 16) & 1u);
  return (unsigned short)(u >> 16);
}

__global__ void setup_kernel(const float *Wattn, const float *Wlin, const float *Wres,
                             const float *ga, const float *ba, const float *ma, const float *va,
                             const float *g1, const float *b1, const float *m1, const float *v1,
                             const float *gl, const float *bl, const float *ml, const float *vl,
                             const float *gr, const float *br, const float *mr, const float *vr,
                             unsigned short *WAf, unsigned short *WLf, unsigned short *WRf,
                             float *saP, float *baP, float *bnf) {
  const int t = blockIdx.x * blockDim.x + threadIdx.x;
  const int stride = gridDim.x * blockDim.x;
  // Wattn fragments, rows permuted to (i*64 + o)
  for (int e = t; e < 6 * 4 * 2 * 64 * 8; e += stride) {
    const int j = e & 7, l = (e >> 3) & 63, ks = (e >> 9) & 1, ot = (e >> 10) & 3, i = e >> 12;
    const int m = l & 15, cg = l >> 4;
    const int cc = ks * 32 + cg * 8 + j;
    const int row = (ot * 16 + m) * CIN + i;  // original Wattn row = o*6+i, o = ot*16+m
    WAf[e] = bf16_rne(Wattn[row * CF + cc]);
  }
  for (int e = t; e < 4 * 2 * 64 * 8; e += stride) {
    const int j = e & 7, l = (e >> 3) & 63, ks = (e >> 9) & 1, ot = e >> 10;
    const int m = l & 15;
    const int cc = ks * 32 + (l >> 4) * 8 + j;
    WLf[e] = bf16_rne(Wlin[(ot * 16 + m) * CF + cc]);
    WRf[e] = bf16_rne(Wres[(ot * 16 + m) * CF + cc]);
  }
  for (int e = t; e < 384; e += stride) {
    const int i = e >> 6, o = e & 63;
    const int j0 = o * CIN + i;
    const float s = ga[j0] * rsqrtf(va[j0] + EPS);
    saP[e] = s;
    baP[e] = ba[j0] - ma[j0] * s;
  }
  for (int e = t; e < 64; e += stride) {
    const float s1v = g1[e] * rsqrtf(v1[e] + EPS);
    bnf[0 * 64 + e] = s1v; bnf[1 * 64 + e] = b1[e] - m1[e] * s1v;
    const float slv = gl[e] * rsqrtf(vl[e] + EPS);
    bnf[2 * 64 + e] = slv; bnf[3 * 64 + e] = bl[e] - ml[e] * slv;
    const float srv = gr[e] * rsqrtf(vr[e] + EPS);
    bnf[4 * 64 + e] = srv; bnf[5 * 64 + e] = br[e] - mr[e] * srv;
  }
}

struct Params {
  const float *x, *y, *points, *feat;
  const float *Wq, *Wpos1, *Wpos2;
  const float *gq, *bq, *mq, *vq;
  const float *gp, *bp, *mp, *vp;
  const unsigned short *WAf, *WLf, *WRf;
  const float *saP, *baP, *bnf;
  float *out;
};

// Gather a bf16 B-fragment (K-dim rows c0..c0+7, output col k) from an fp32 LDS
// buffer with row stride LS.  Truncation bf16 pack (error ~2^-8, well under thr).
__device__ inline bf16x8 load_bfrag(const float *S, int c0, int k) {
  unsigned u[4];
#pragma unroll
  for (int pp = 0; pp < 4; ++pp) {
    const float f0 = S[(c0 + 2 * pp) * LS + k];
    const float f1 = S[(c0 + 2 * pp + 1) * LS + k];
    u[pp] = (__builtin_bit_cast(unsigned, f0) >> 16) |
            (__builtin_bit_cast(unsigned, f1) & 0xffff0000u);
  }
  uint4 q = make_uint4(u[0], u[1], u[2], u[3]);
  return __builtin_bit_cast(bf16x8, q);
}

__global__ __launch_bounds__(256) void fused_pt_attn(Params p) {
  const int bn = blockIdx.x;
  const int b  = bn >> 11;          // NPT == 2048
  const int n  = bn & (NPT - 1);
  const int tid = threadIdx.x;

  __shared__ __align__(16) float s_y[CF * LS];     // y[b,:,n,:] fp32
  __shared__ __align__(16) float s_attn[CF * LS];  // softmax out; reused as h
  __shared__ __align__(16) float s_x[CIN * KNN];
  __shared__ float s_xq[CF];
  __shared__ float s_pos[CIN];
  __shared__ float s_feat[CF / 2];
  __shared__ float s_pts[CIN / 2];
  __shared__ float s_w2[CF * CIN];

  const int cth = tid >> 2;          // 0..63 (channel for staging/softmax)
  const int kg  = tid & 3;
  const int k0  = kg * 8;

  // ---------------- phase 0: stage inputs ----------------
  {
    const float *yrow = p.y + (((size_t)(b * CF + cth)) * NPT + n) * KNN + k0;
    const float4 v0 = *(const float4 *)(yrow);
    const float4 v1 = *(const float4 *)(yrow + 4);
    float *d = s_y + cth * LS + k0;
    d[0] = v0.x; d[1] = v0.y; d[2] = v0.z; d[3] = v0.w;
    d[4] = v1.x; d[5] = v1.y; d[6] = v1.z; d[7] = v1.w;

    if (tid < CIN * KNN) {
      const int i = tid >> 5, k = tid & 31;
      s_x[tid] = p.x[(((size_t)b * CIN + i) * NPT + n) * KNN + k];
    }
    if (tid >= 192 && tid < 192 + CF / 2) {
      const int c = tid - 192;
      s_feat[c] = p.feat[((size_t)b * (CF / 2) + c) * NPT + n];
    }
    if (tid >= 224 && tid < 224 + CIN / 2) {
      const int i = tid - 224;
      s_pts[i] = p.points[((size_t)b * (CIN / 2) + i) * NPT + n];
    }
    for (int t2 = tid; t2 < CF * CIN; t2 += 256) s_w2[t2] = p.Wpos2[t2];
  }
  __syncthreads();

  // ---------------- phase 1: x_q and pos (BN+lrelu) ----------------
  if (tid < CF) {
    float acc = 0.f;
    const float *wrow = p.Wq + tid * (CF / 2);
#pragma unroll
    for (int i = 0; i < CF / 2; i += 4) {
      const float4 w = *(const float4 *)(wrow + i);
      acc += w.x * s_feat[i] + w.y * s_feat[i + 1] + w.z * s_feat[i + 2] + w.w * s_feat[i + 3];
    }
    const float s = p.gq[tid] * rsqrtf(p.vq[tid] + EPS);
    const float v = acc * s + (p.bq[tid] - p.mq[tid] * s);
    s_xq[tid] = v > 0.f ? v : 0.2f * v;
  } else if (tid < CF + CIN) {
    const int i = tid - CF;
    float acc = 0.f;
#pragma unroll
    for (int ci = 0; ci < CIN / 2; ++ci) acc += p.Wpos1[i * (CIN / 2) + ci] * s_pts[ci];
    const float s = p.gp[i] * rsqrtf(p.vp[i] + EPS);
    const float v = acc * s + (p.bp[i] - p.mp[i] * s);
    s_pos[i] = v > 0.f ? v : 0.2f * v;
  }
  __syncthreads();

  // ---------------- phase 2: attn_pre + softmax over k ----------------
  {
    float w2[CIN];
#pragma unroll
    for (int i = 0; i < CIN; ++i) w2[i] = s_w2[cth * CIN + i];
    const float xq = s_xq[cth];
    float pre[8];
#pragma unroll
    for (int m = 0; m < 8; ++m) {
      const int k = k0 + m;
      float v = xq - s_y[cth * LS + k];
#pragma unroll
      for (int i = 0; i < CIN; ++i) v += w2[i] * (s_pos[i] - s_x[i * KNN + k]);
      pre[m] = v * 0.125f;  // 1/sqrt(Cf)
    }
    float mx = pre[0];
#pragma unroll
    for (int m = 1; m < 8; ++m) mx = fmaxf(mx, pre[m]);
    mx = fmaxf(mx, __shfl_xor(mx, 1));
    mx = fmaxf(mx, __shfl_xor(mx, 2));
    float sum = 0.f;
#pragma unroll
    for (int m = 0; m < 8; ++m) { pre[m] = __expf(pre[m] - mx); sum += pre[m]; }
    sum += __shfl_xor(sum, 1);
    sum += __shfl_xor(sum, 2);
    const float inv = 1.f / sum;
#pragma unroll
    for (int m = 0; m < 8; ++m) s_attn[cth * LS + k0 + m] = pre[m] * inv;
  }
  __syncthreads();

  // ---------------- phase 3: GEMM1 via MFMA + BN_a + x-combine + BN_1 ----------------
  const int lane = tid & 63;
  const int ot   = tid >> 6;        // wave id == o-tile (0..3)
  const int og   = lane >> 4;       // k-group of lane
  const int kl   = lane & 15;       // output col within tile

  // B-fragments of attn: [ks][nt]
  bf16x8 Ba[2][2];
#pragma unroll
  for (int ks = 0; ks < 2; ++ks)
#pragma unroll
    for (int nt = 0; nt < 2; ++nt)
      Ba[ks][nt] = load_bfrag(s_attn, ks * 32 + og * 8, kl + nt * 16);

  f32x4 outa[2];
#pragma unroll
  for (int nt = 0; nt < 2; ++nt) outa[nt] = (f32x4){0.f, 0.f, 0.f, 0.f};

  const bf16x8 *WAv = (const bf16x8 *)p.WAf;
#pragma unroll
  for (int i = 0; i < CIN; ++i) {
    const bf16x8 A0 = WAv[((i * 4 + ot) * 2 + 0) * 64 + lane];
    const bf16x8 A1 = WAv[((i * 4 + ot) * 2 + 1) * 64 + lane];
    const f32x4 sa4 = *(const f32x4 *)(p.saP + i * 64 + ot * 16 + og * 4);
    const f32x4 ba4 = *(const f32x4 *)(p.baP + i * 64 + ot * 16 + og * 4);
#pragma unroll
    for (int nt = 0; nt < 2; ++nt) {
      f32x4 g = {0.f, 0.f, 0.f, 0.f};
      g = __builtin_amdgcn_mfma_f32_16x16x32_bf16(A0, Ba[0][nt], g, 0, 0, 0);
      g = __builtin_amdgcn_mfma_f32_16x16x32_bf16(A1, Ba[1][nt], g, 0, 0, 0);
      const float xv = s_x[i * KNN + kl + nt * 16];
#pragma unroll
      for (int r = 0; r < 4; ++r)
        outa[nt][r] = fmaf(fmaf(sa4[r], g[r], ba4[r]), xv, outa[nt][r]);
    }
  }

  // BN1 + lrelu -> h
  float hv[2][4];
  {
    const f32x4 s14 = *(const f32x4 *)(p.bnf + 0 * 64 + ot * 16 + og * 4);
    const f32x4 b14 = *(const f32x4 *)(p.bnf + 1 * 64 + ot * 16 + og * 4);
#pragma unroll
    for (int nt = 0; nt < 2; ++nt)
#pragma unroll
      for (int r = 0; r < 4; ++r) {
        const float tv = fmaf(s14[r], outa[nt][r], b14[r]);
        hv[nt][r] = tv > 0.f ? tv : 0.2f * tv;
      }
  }
  __syncthreads();  // all waves done reading s_attn
#pragma unroll
  for (int nt = 0; nt < 2; ++nt)
#pragma unroll
    for (int r = 0; r < 4; ++r)
      s_attn[(ot * 16 + og * 4 + r) * LS + kl + nt * 16] = hv[nt][r];  // h aliases attn
  __syncthreads();

  // ---------------- phase 4: GEMM2 (Wlin@h) + res (Wres@y) via MFMA ----------------
  {
    const bf16x8 *WLv = (const bf16x8 *)p.WLf;
    const bf16x8 *WRv = (const bf16x8 *)p.WRf;
    const bf16x8 L0 = WLv[((ot * 2 + 0) * 64) + lane];
    const bf16x8 L1 = WLv[((ot * 2 + 1) * 64) + lane];
    const bf16x8 R0 = WRv[((ot * 2 + 0) * 64) + lane];
    const bf16x8 R1 = WRv[((ot * 2 + 1) * 64) + lane];

    const f32x4 sl4 = *(const f32x4 *)(p.bnf + 2 * 64 + ot * 16 + og * 4);
    const f32x4 bl4 = *(const f32x4 *)(p.bnf + 3 * 64 + ot * 16 + og * 4);
    const f32x4 sr4 = *(const f32x4 *)(p.bnf + 4 * 64 + ot * 16 + og * 4);
    const f32x4 br4 = *(const f32x4 *)(p.bnf + 5 * 64 + ot * 16 + og * 4);

#pragma unroll
    for (int nt = 0; nt < 2; ++nt) {
      const bf16x8 Bh0 = load_bfrag(s_attn, 0 * 32 + og * 8, kl + nt * 16);
      const bf16x8 Bh1 = load_bfrag(s_attn, 1 * 32 + og * 8, kl + nt * 16);
      const bf16x8 By0 = load_bfrag(s_y,    0 * 32 + og * 8, kl + nt * 16);
      const bf16x8 By1 = load_bfrag(s_y,    1 * 32 + og * 8, kl + nt * 16);
      f32x4 a2 = {0.f, 0.f, 0.f, 0.f};
      a2 = __builtin_amdgcn_mfma_f32_16x16x32_bf16(L0, Bh0, a2, 0, 0, 0);
      a2 = __builtin_amdgcn_mfma_f32_16x16x32_bf16(L1, Bh1, a2, 0, 0, 0);
      f32x4 a3 = {0.f, 0.f, 0.f, 0.f};
      a3 = __builtin_amdgcn_mfma_f32_16x16x32_bf16(R0, By0, a3, 0, 0, 0);
      a3 = __builtin_amdgcn_mfma_f32_16x16x32_bf16(R1, By1, a3, 0, 0, 0);

      float *obase = p.out + (((size_t)(b * CO + ot * 16 + og * 4)) * NPT + n) * KNN
                     + kl + nt * 16;
#pragma unroll
      for (int r = 0; r < 4; ++r) {
        const float v = fmaf(sl4[r], a2[r], bl4[r]) + fmaf(sr4[r], a3[r], br4[r]);
        obase[(size_t)r * NPT * KNN] = v > 0.f ? v : 0.2f * v;
      }
    }
  }
}

extern "C" void kernel_launch(void *const *d_in, const int *in_sizes, int n_in,
                              void *d_out, int out_size, void *d_ws, size_t ws_size,
                              hipStream_t stream) {
  char *ws = (char *)d_ws;
  unsigned short *WAf = (unsigned short *)(ws + WS_WA);
  unsigned short *WLf = (unsigned short *)(ws + WS_WL);
  unsigned short *WRf = (unsigned short *)(ws + WS_WR);
  float *saP = (float *)(ws + WS_SA);
  float *baP = (float *)(ws + WS_BA);
  float *bnf = (float *)(ws + WS_BNF);

  setup_kernel<<<dim3(96), dim3(256), 0, stream>>>(
      (const float *)d_in[7], (const float *)d_in[8], (const float *)d_in[9],
      (const float *)d_in[18], (const float *)d_in[19], (const float *)d_in[20], (const float *)d_in[21],
      (const float *)d_in[22], (const float *)d_in[23], (const float *)d_in[24], (const float *)d_in[25],
      (const float *)d_in[26], (const float *)d_in[27], (const float *)d_in[28], (const float *)d_in[29],
      (const float *)d_in[30], (const float *)d_in[31], (const float *)d_in[32], (const float *)d_in[33],
      WAf, WLf, WRf, saP, baP, bnf);

  Params p;
  p.x      = (const float *)d_in[0];
  p.y      = (const float *)d_in[1];
  p.points = (const float *)d_in[2];
  p.feat   = (const float *)d_in[3];
  p.Wq     = (const float *)d_in[4];
  p.Wpos1  = (const float *)d_in[5];
  p.Wpos2  = (const float *)d_in[6];
  p.gq = (const float *)d_in[10]; p.bq = (const float *)d_in[11];
  p.mq = (const float *)d_in[12]; p.vq = (const float *)d_in[13];
  p.gp = (const float *)d_in[14]; p.bp = (const float *)d_in[15];
  p.mp = (const float *)d_in[16]; p.vp = (const float *)d_in[17];
  p.WAf = WAf; p.WLf = WLf; p.WRf = WRf;
  p.saP = saP; p.baP = baP; p.bnf = bnf;
  p.out = (float *)d_out;

  fused_pt_attn<<<dim3(NB * NPT), dim3(256), 0, stream>>>(p);
}

// Round 3
// 66.884 us; speedup vs baseline: 3.9985x; 1.2880x over previous
//
#include <hip/hip_runtime.h>

// Problem constants (fixed by setup_inputs)
constexpr int NB  = 4;     // batch
constexpr int NPT = 2048;  // points (N)
constexpr int KNN = 32;    // neighbors (K)
constexpr int CIN = 6;     // in_channels
constexpr int CF  = 64;    // feat channels
constexpr int CO  = 64;    // out channels
constexpr float EPS = 1e-5f;

typedef short bf16x8 __attribute__((ext_vector_type(8)));   // 8 bf16 in 4 VGPRs
typedef float f32x4  __attribute__((ext_vector_type(4)));

// ---------------- workspace layout (bytes) ----------------
// 0      : WAf bf16[6*4*2*64*8] (sa-folded, row-permuted)   49152 B
// 49152  : WLf bf16[4*2*64*8]  (sl-folded)                   8192 B
// 57344  : WRf bf16[4*2*64*8]  (sr-folded)                   8192 B
// 65536  : baP f32[6*64]                                     1536 B
// 67072  : bnf f32[3*64]  (s1, b1, blr)                       768 B
constexpr size_t WS_WA  = 0;
constexpr size_t WS_WL  = 49152;
constexpr size_t WS_WR  = 57344;
constexpr size_t WS_BA  = 65536;
constexpr size_t WS_BNF = 67072;

__device__ __host__ inline unsigned short bf16_rne(float f) {
  unsigned u = __builtin_bit_cast(unsigned, f);
  u += 0x7fffu + ((u >> 16) & 1u);
  return (unsigned short)(u >> 16);
}

__global__ void setup_kernel(const float *Wattn, const float *Wlin, const float *Wres,
                             const float *ga, const float *ba, const float *ma, const float *va,
                             const float *g1, const float *b1, const float *m1, const float *v1,
                             const float *gl, const float *bl, const float *ml, const float *vl,
                             const float *gr, const float *br, const float *mr, const float *vr,
                             unsigned short *WAf, unsigned short *WLf, unsigned short *WRf,
                             float *baP, float *bnf) {
  const int t = blockIdx.x * blockDim.x + threadIdx.x;
  const int stride = gridDim.x * blockDim.x;
  // Wattn fragments: rows permuted to (i major), BN_a scale folded in.
  for (int e = t; e < 6 * 4 * 2 * 64 * 8; e += stride) {
    const int j = e & 7, l = (e >> 3) & 63, ks = (e >> 9) & 1, ot = (e >> 10) & 3, i = e >> 12;
    const int m = l & 15, cg = l >> 4;
    const int cc = ks * 32 + cg * 8 + j;
    const int row = (ot * 16 + m) * CIN + i;
    const float sa = ga[row] * rsqrtf(va[row] + EPS);
    WAf[e] = bf16_rne(Wattn[row * CF + cc] * sa);
  }
  for (int e = t; e < 4 * 2 * 64 * 8; e += stride) {
    const int j = e & 7, l = (e >> 3) & 63, ks = (e >> 9) & 1, ot = e >> 10;
    const int m = l & 15;
    const int cc = ks * 32 + (l >> 4) * 8 + j;
    const int row = ot * 16 + m;
    const float sl = gl[row] * rsqrtf(vl[row] + EPS);
    const float sr = gr[row] * rsqrtf(vr[row] + EPS);
    WLf[e] = bf16_rne(Wlin[row * CF + cc] * sl);
    WRf[e] = bf16_rne(Wres[row * CF + cc] * sr);
  }
  for (int e = t; e < 384; e += stride) {
    const int i = e >> 6, o = e & 63;
    const int j0 = o * CIN + i;
    const float sa = ga[j0] * rsqrtf(va[j0] + EPS);
    baP[e] = ba[j0] - ma[j0] * sa;
  }
  for (int e = t; e < 64; e += stride) {
    const float s1v = g1[e] * rsqrtf(v1[e] + EPS);
    bnf[e]      = s1v;
    bnf[64 + e] = b1[e] - m1[e] * s1v;
    const float slv = gl[e] * rsqrtf(vl[e] + EPS);
    const float srv = gr[e] * rsqrtf(vr[e] + EPS);
    bnf[128 + e] = (bl[e] - ml[e] * slv) + (br[e] - mr[e] * srv);
  }
}

struct Params {
  const float *x, *y, *points, *feat;
  const float *Wq, *Wpos1, *Wpos2;
  const float *gq, *bq, *mq, *vq;
  const float *gp, *bp, *mp, *vp;
  const unsigned short *WAf, *WLf, *WRf;
  const float *baP, *bnf;
  float *out;
};

// One wave per point; no block barriers (per-wave LDS partitions; DS ops are
// in-order within a wave, so same-wave producer->consumer via LDS is safe).
__global__ __launch_bounds__(256) void fused_pt_attn(Params p) {
  const int tid  = threadIdx.x;
  const int lane = tid & 63;
  const int wid  = tid >> 6;
  // XCD-aware swizzle: 2048 blocks, 8 XCDs -> each XCD gets a contiguous range.
  const int bid  = ((blockIdx.x & 7) << 8) + (blockIdx.x >> 3);
  const int pidx = bid * 4 + wid;
  const int b    = pidx >> 11;
  const int n    = pidx & (NPT - 1);

  // per-wave LDS: yB (bf16 [k][c] swizzled, 4KB) + PB (same, 4KB) + d + feat
  __shared__ unsigned short s_B[4][2 * 2048];
  __shared__ float s_d[4][192];
  __shared__ float s_f[4][32];
  unsigned short *yB = s_B[wid];
  unsigned short *PB = s_B[wid] + 2048;
  float *dW = s_d[wid];
  float *fW = s_f[wid];

  // ---- stage: issue global loads ----
  float ftv = 0.f, ptv = 0.f;
  if (lane < 32) ftv = p.feat[((size_t)b * 32 + lane) * NPT + n];
  if (lane < 3)  ptv = p.points[((size_t)b * 3 + lane) * NPT + n];
  const int xi = lane >> 3, xk = (lane & 7) * 4;
  float4 x4 = make_float4(0.f, 0.f, 0.f, 0.f);
  if (lane < 48)
    x4 = *(const float4 *)(p.x + (((size_t)b * CIN + xi) * NPT + n) * KNN + xk);
  const float *w2p = p.Wpos2 + lane * 6;   // Wpos2[c][i], row per lane channel
  const float2 w2a = *(const float2 *)(w2p);
  const float2 w2b = *(const float2 *)(w2p + 2);
  const float2 w2c = *(const float2 *)(w2p + 4);
  const float w2[6] = {w2a.x, w2a.y, w2b.x, w2b.y, w2c.x, w2c.y};

  if (lane < 32) fW[lane] = ftv;

  // ---- pos1 (computed redundantly in all lanes; needs points broadcast) ----
  const float pt0 = __shfl(ptv, 0), pt1 = __shfl(ptv, 1), pt2 = __shfl(ptv, 2);
  float pos1[6];
#pragma unroll
  for (int i = 0; i < 6; ++i) {
    const float a = p.Wpos1[i * 3 + 0] * pt0 + p.Wpos1[i * 3 + 1] * pt1 +
                    p.Wpos1[i * 3 + 2] * pt2;
    const float s = p.gp[i] * rsqrtf(p.vp[i] + EPS);
    const float v = fmaf(a, s, p.bp[i] - p.mp[i] * s);
    pos1[i] = v > 0.f ? v : 0.2f * v;
  }

  // ---- d[i][k] = pos1[i] - x[i][k]  (lanes 0..47 write 4 elems each) ----
  if (lane < 48) {
    float pi = pos1[0];
    pi = (xi == 1) ? pos1[1] : pi;
    pi = (xi == 2) ? pos1[2] : pi;
    pi = (xi == 3) ? pos1[3] : pi;
    pi = (xi == 4) ? pos1[4] : pi;
    pi = (xi == 5) ? pos1[5] : pi;
    *(float4 *)(dW + xi * 32 + xk) =
        make_float4(pi - x4.x, pi - x4.y, pi - x4.z, pi - x4.w);
  }

  // ---- x_q[lane] ----
  float xq;
  {
    float acc = 0.f;
    const float *wq = p.Wq + lane * 32;
#pragma unroll
    for (int q = 0; q < 8; ++q) {
      const float4 w4 = *(const float4 *)(wq + q * 4);
      const float4 f4 = *(const float4 *)(fW + q * 4);
      acc = fmaf(w4.x, f4.x, fmaf(w4.y, f4.y, fmaf(w4.z, f4.z, fmaf(w4.w, f4.w, acc))));
    }
    const float s = p.gq[lane] * rsqrtf(p.vq[lane] + EPS);
    const float v = fmaf(acc, s, p.bq[lane] - p.mq[lane] * s);
    xq = v > 0.f ? v : 0.2f * v;
  }

  // ---- pre[k] = sum_i w2[i]*d[i][k]  (broadcast b128 reads) ----
  float pre[32];
#pragma unroll
  for (int k = 0; k < 32; ++k) pre[k] = 0.f;
#pragma unroll
  for (int i = 0; i < 6; ++i) {
    const float wv = w2[i];
#pragma unroll
    for (int q = 0; q < 8; ++q) {
      const float4 d4 = *(const float4 *)(dW + i * 32 + q * 4);
      pre[q * 4 + 0] = fmaf(wv, d4.x, pre[q * 4 + 0]);
      pre[q * 4 + 1] = fmaf(wv, d4.y, pre[q * 4 + 1]);
      pre[q * 4 + 2] = fmaf(wv, d4.z, pre[q * 4 + 2]);
      pre[q * 4 + 3] = fmaf(wv, d4.w, pre[q * 4 + 3]);
    }
  }

  // ---- stream y: finalize pre, stash y as bf16 B-frag layout ----
  const float *yrow = p.y + (((size_t)b * CF + lane) * NPT + n) * KNN;
#pragma unroll
  for (int q = 0; q < 8; ++q) {
    const float4 y4 = *(const float4 *)(yrow + q * 4);
    const float yv[4] = {y4.x, y4.y, y4.z, y4.w};
#pragma unroll
    for (int j = 0; j < 4; ++j) {
      const int k = q * 4 + j;
      yB[k * 64 + (lane ^ ((k & 7) << 3))] = bf16_rne(yv[j]);
      pre[k] = (xq - yv[j] + pre[k]) * 0.125f;
    }
  }

  // ---- in-lane softmax over k ----
  float mx = pre[0];
#pragma unroll
  for (int k = 1; k < 32; ++k) mx = fmaxf(mx, pre[k]);
  float sum = 0.f;
#pragma unroll
  for (int k = 0; k < 32; ++k) { pre[k] = __expf(pre[k] - mx); sum += pre[k]; }
  const float inv = 1.f / sum;
#pragma unroll
  for (int k = 0; k < 32; ++k)
    PB[k * 64 + (lane ^ ((k & 7) << 3))] = bf16_rne(pre[k] * inv);

  // ---- MFMA phase ----
  const int og = lane >> 4, kl = lane & 15;

  // x values for the combine: x[i][kcol] = pos1[i] - d[i][kcol]
  float xvv[6][2];
#pragma unroll
  for (int i = 0; i < 6; ++i)
#pragma unroll
    for (int nt = 0; nt < 2; ++nt)
      xvv[i][nt] = pos1[i] - dW[i * 32 + kl + nt * 16];

  // B-fragments of P (one conflict-free ds_read_b128 each)
  bf16x8 Ba[2][2];
#pragma unroll
  for (int ks = 0; ks < 2; ++ks)
#pragma unroll
    for (int nt = 0; nt < 2; ++nt) {
      const int kcol = kl + nt * 16;
      Ba[ks][nt] = *(const bf16x8 *)(PB + kcol * 64 + ((ks * 32 + og * 8) ^ ((kcol & 7) << 3)));
    }

  // GEMM1 per o-tile, fused BN_a(bias) + x-combine + BN1 + lrelu + h-write
  const bf16x8 *WAv = (const bf16x8 *)p.WAf;
#pragma unroll
  for (int ot = 0; ot < 4; ++ot) {
    float out1[2][4] = {{0.f, 0.f, 0.f, 0.f}, {0.f, 0.f, 0.f, 0.f}};
#pragma unroll
    for (int i = 0; i < 6; ++i) {
      const bf16x8 A0 = WAv[((i * 4 + ot) * 2 + 0) * 64 + lane];
      const bf16x8 A1 = WAv[((i * 4 + ot) * 2 + 1) * 64 + lane];
      const f32x4 ba4 = *(const f32x4 *)(p.baP + i * 64 + ot * 16 + og * 4);
#pragma unroll
      for (int nt = 0; nt < 2; ++nt) {
        f32x4 g = {0.f, 0.f, 0.f, 0.f};
        g = __builtin_amdgcn_mfma_f32_16x16x32_bf16(A0, Ba[0][nt], g, 0, 0, 0);
        g = __builtin_amdgcn_mfma_f32_16x16x32_bf16(A1, Ba[1][nt], g, 0, 0, 0);
        const float xv = xvv[i][nt];
#pragma unroll
        for (int r = 0; r < 4; ++r)
          out1[nt][r] = fmaf(g[r] + ba4[r], xv, out1[nt][r]);
      }
    }
    const f32x4 s14 = *(const f32x4 *)(p.bnf + 0 * 64 + ot * 16 + og * 4);
    const f32x4 b14 = *(const f32x4 *)(p.bnf + 1 * 64 + ot * 16 + og * 4);
#pragma unroll
    for (int nt = 0; nt < 2; ++nt) {
      const int kcol = kl + nt * 16;
      unsigned hp[4];
#pragma unroll
      for (int r = 0; r < 4; ++r) {
        const float t = fmaf(s14[r], out1[nt][r], b14[r]);
        hp[r] = bf16_rne(t > 0.f ? t : 0.2f * t);
      }
      const int idx = kcol * 64 + ((ot * 16 + og * 4) ^ ((kcol & 7) << 3));
      *(uint2 *)(PB + idx) = make_uint2(hp[0] | (hp[1] << 16), hp[2] | (hp[3] << 16));
    }
  }

  // GEMM2: out = lrelu( Wlin'@h + Wres'@y + blr )  (one 4-MFMA chain)
  bf16x8 Bh[2][2], By[2][2];
#pragma unroll
  for (int ks = 0; ks < 2; ++ks)
#pragma unroll
    for (int nt = 0; nt < 2; ++nt) {
      const int kcol = kl + nt * 16;
      const int off = kcol * 64 + ((ks * 32 + og * 8) ^ ((kcol & 7) << 3));
      Bh[ks][nt] = *(const bf16x8 *)(PB + off);
      By[ks][nt] = *(const bf16x8 *)(yB + off);
    }
  const bf16x8 *WLv = (const bf16x8 *)p.WLf;
  const bf16x8 *WRv = (const bf16x8 *)p.WRf;
#pragma unroll
  for (int ot = 0; ot < 4; ++ot) {
    const bf16x8 L0 = WLv[(ot * 2 + 0) * 64 + lane];
    const bf16x8 L1 = WLv[(ot * 2 + 1) * 64 + lane];
    const bf16x8 R0 = WRv[(ot * 2 + 0) * 64 + lane];
    const bf16x8 R1 = WRv[(ot * 2 + 1) * 64 + lane];
    const f32x4 blr = *(const f32x4 *)(p.bnf + 2 * 64 + ot * 16 + og * 4);
#pragma unroll
    for (int nt = 0; nt < 2; ++nt) {
      f32x4 a = {0.f, 0.f, 0.f, 0.f};
      a = __builtin_amdgcn_mfma_f32_16x16x32_bf16(L0, Bh[0][nt], a, 0, 0, 0);
      a = __builtin_amdgcn_mfma_f32_16x16x32_bf16(L1, Bh[1][nt], a, 0, 0, 0);
      a = __builtin_amdgcn_mfma_f32_16x16x32_bf16(R0, By[0][nt], a, 0, 0, 0);
      a = __builtin_amdgcn_mfma_f32_16x16x32_bf16(R1, By[1][nt], a, 0, 0, 0);
      const int kcol = kl + nt * 16;
      float *ob = p.out + (((size_t)(b * CO + ot * 16 + og * 4)) * NPT + n) * KNN + kcol;
#pragma unroll
      for (int r = 0; r < 4; ++r) {
        const float v = a[r] + blr[r];
        ob[(size_t)r * NPT * KNN] = v > 0.f ? v : 0.2f * v;
      }
    }
  }
}

extern "C" void kernel_launch(void *const *d_in, const int *in_sizes, int n_in,
                              void *d_out, int out_size, void *d_ws, size_t ws_size,
                              hipStream_t stream) {
  char *ws = (char *)d_ws;
  unsigned short *WAf = (unsigned short *)(ws + WS_WA);
  unsigned short *WLf = (unsigned short *)(ws + WS_WL);
  unsigned short *WRf = (unsigned short *)(ws + WS_WR);
  float *baP = (float *)(ws + WS_BA);
  float *bnf = (float *)(ws + WS_BNF);

  setup_kernel<<<dim3(96), dim3(256), 0, stream>>>(
      (const float *)d_in[7], (const float *)d_in[8], (const float *)d_in[9],
      (const float *)d_in[18], (const float *)d_in[19], (const float *)d_in[20], (const float *)d_in[21],
      (const float *)d_in[22], (const float *)d_in[23], (const float *)d_in[24], (const float *)d_in[25],
      (const float *)d_in[26], (const float *)d_in[27], (const float *)d_in[28], (const float *)d_in[29],
      (const float *)d_in[30], (const float *)d_in[31], (const float *)d_in[32], (const float *)d_in[33],
      WAf, WLf, WRf, baP, bnf);

  Params p;
  p.x      = (const float *)d_in[0];
  p.y      = (const float *)d_in[1];
  p.points = (const float *)d_in[2];
  p.feat   = (const float *)d_in[3];
  p.Wq     = (const float *)d_in[4];
  p.Wpos1  = (const float *)d_in[5];
  p.Wpos2  = (const float *)d_in[6];
  p.gq = (const float *)d_in[10]; p.bq = (const float *)d_in[11];
  p.mq = (const float *)d_in[12]; p.vq = (const float *)d_in[13];
  p.gp = (const float *)d_in[14]; p.bp = (const float *)d_in[15];
  p.mp = (const float *)d_in[16]; p.vp = (const float *)d_in[17];
  p.WAf = WAf; p.WLf = WLf; p.WRf = WRf;
  p.baP = baP; p.bnf = bnf;
  p.out = (float *)d_out;

  fused_pt_attn<<<dim3(NB * NPT / 4), dim3(256), 0, stream>>>(p);
}